// Round 1
// baseline (8712.595 us; speedup 1.0000x reference)
//
#include <hip/hip_runtime.h>
#include <math.h>

// DCGRU encoder, fp32 correctness-first baseline.
// B=16 T=32 N=128 D=H=128, K=2 diffusion steps (M=3), L=2 layers, 1 support.
//
// Per step (layer l, time t):
//   cat  = [x_t | h]                         [B,N,256]
//   D1   = S_t @ cat   (per b)               [B,N,256]
//   D2   = 2 S_t @ D1 - cat                  [B,N,256]
//   g    = sigmoid([cat|D1|D2] @ Wgr + bg)   [B,N,256]   (Wgr: rows reordered m*256+d)
//   r,u  = g[:, :128], g[:, 128:];  rh = r*h
//   cat2 = [x_t | rh];  D1',D2' likewise
//   c    = tanh([cat2|D1'|D2'] @ Wcr + bc)   [B,N,128]
//   h    = u*h + (1-u)*c
// Outputs: d_out = [finals (L,B,N*H) | layer-1 seq (T,B,N*H)]

namespace {
constexpr int B = 16, T = 32, N = 128, D = 128, H = 128;
constexpr int CATF = 256;       // D + H
constexpr int K3 = 768;         // CATF * 3
constexpr int OG = 256;         // 2H (gates out)
constexpr int OC = 128;         // H  (candidate out)
constexpr int ROWS = B * N;     // 2048
}

// Rearrange weights: original row index (d*3 + m) -> new row index (m*256 + d),
// so the GEMM A-operand can be the contiguous concat [cat | D1 | D2].
__global__ __launch_bounds__(256) void prep_weights_k(
    const float* __restrict__ Wg0, const float* __restrict__ Wc0,
    const float* __restrict__ Wg1, const float* __restrict__ Wc1,
    float* __restrict__ Wgr, float* __restrict__ Wcr) {
  const int stride = gridDim.x * blockDim.x;
  const int tid0 = blockIdx.x * blockDim.x + threadIdx.x;
  for (int idx = tid0; idx < 2 * K3 * OG; idx += stride) {
    int l = idx / (K3 * OG);
    int rem = idx - l * (K3 * OG);
    int r = rem / OG, o = rem - r * OG;
    int m = r / CATF, d = r - m * CATF;
    const float* W = l ? Wg1 : Wg0;
    Wgr[idx] = W[(d * 3 + m) * OG + o];
  }
  for (int idx = tid0; idx < 2 * K3 * OC; idx += stride) {
    int l = idx / (K3 * OC);
    int rem = idx - l * (K3 * OC);
    int r = rem / OC, o = rem - r * OC;
    int m = r / CATF, d = r - m * CATF;
    const float* W = l ? Wc1 : Wc0;
    Wcr[idx] = W[(d * 3 + m) * OC + o];
  }
}

__global__ __launch_bounds__(256) void copy_k(const float* __restrict__ src,
                                              float* __restrict__ dst, int n) {
  const int stride = gridDim.x * blockDim.x;
  for (int i = blockIdx.x * blockDim.x + threadIdx.x; i < n; i += stride)
    dst[i] = src[i];
}

// D1 = S @ cat, D2 = 2 S @ D1 - cat, for one (b, 32-feature block).
// cat[b,n,f] = f<128 ? xbase[b*xbs + n*128 + f] : hsrc[(b*128+n)*128 + f-128]
// grid: 128 blocks = 16 b x 8 feature-blocks; 256 threads.
__global__ __launch_bounds__(256) void diffusion_k(
    const float* __restrict__ S, const float* __restrict__ xbase, long xbs,
    const float* __restrict__ hsrc,
    float* __restrict__ D1, float* __restrict__ D2) {
  __shared__ float Sl[N][133];     // S row-major, padded (ld%4!=0: conflict-free)
  __shared__ float catb[N][34];
  __shared__ float tmpb[N][34];
  const int b  = blockIdx.x >> 3;
  const int d0 = (blockIdx.x & 7) * 32;
  const int tid = threadIdx.x;

  for (int i = tid; i < N * N; i += 256) {
    int m = i >> 7, n = i & 127;
    Sl[m][n] = S[i];
  }
  for (int i = tid; i < N * 32; i += 256) {
    int n = i >> 5, c = i & 31;
    int f = d0 + c;
    catb[n][c] = (f < D) ? xbase[(long)b * xbs + n * D + f]
                         : hsrc[((b * N + n) << 7) + (f - D)];
  }
  __syncthreads();

  const int m0 = (tid >> 4) * 8;   // 8 output rows per thread
  const int c0 = (tid & 15) * 2;   // 2 output cols per thread
  float a0[8], a1[8];
#pragma unroll
  for (int i = 0; i < 8; i++) { a0[i] = 0.f; a1[i] = 0.f; }
#pragma unroll 2
  for (int n = 0; n < N; n++) {
    float v0 = catb[n][c0], v1 = catb[n][c0 + 1];
#pragma unroll
    for (int i = 0; i < 8; i++) {
      float s = Sl[m0 + i][n];
      a0[i] += s * v0;
      a1[i] += s * v1;
    }
  }
#pragma unroll
  for (int i = 0; i < 8; i++) {
    tmpb[m0 + i][c0]     = a0[i];
    tmpb[m0 + i][c0 + 1] = a1[i];
  }
  __syncthreads();

  // coalesced D1 store
  for (int i = tid; i < N * 32; i += 256) {
    int n = i >> 5, c = i & 31;
    D1[((b * N + n) << 8) + d0 + c] = tmpb[n][c];
  }
  // D2 accumulate: S @ D1
  float b0[8], b1[8];
#pragma unroll
  for (int i = 0; i < 8; i++) { b0[i] = 0.f; b1[i] = 0.f; }
#pragma unroll 2
  for (int n = 0; n < N; n++) {
    float v0 = tmpb[n][c0], v1 = tmpb[n][c0 + 1];
#pragma unroll
    for (int i = 0; i < 8; i++) {
      float s = Sl[m0 + i][n];
      b0[i] += s * v0;
      b1[i] += s * v1;
    }
  }
  __syncthreads();                 // everyone done reading tmpb
#pragma unroll
  for (int i = 0; i < 8; i++) {
    tmpb[m0 + i][c0]     = 2.f * b0[i] - catb[m0 + i][c0];
    tmpb[m0 + i][c0 + 1] = 2.f * b1[i] - catb[m0 + i][c0 + 1];
  }
  __syncthreads();
  for (int i = tid; i < N * 32; i += 256) {
    int n = i >> 5, c = i & 31;
    D2[((b * N + n) << 8) + d0 + c] = tmpb[n][c];
  }
}

// gates = sigmoid([cat|D1|D2] @ Wgr + bg); write rh = r*h (o<128) and u (o>=128).
// grid: 256 blocks = 128 row-blocks(16 rows) x 2 o-halves(128); 256 threads.
__global__ __launch_bounds__(256) void gates_k(
    const float* __restrict__ xbase, long xbs,
    const float* __restrict__ h,
    const float* __restrict__ D1, const float* __restrict__ D2,
    const float* __restrict__ Wgr, const float* __restrict__ bg,
    float* __restrict__ rh, float* __restrict__ u) {
  __shared__ float Al[16][K3];
  const int row0 = (blockIdx.x >> 1) * 16;
  const int ob   = (blockIdx.x & 1) * 128;
  const int tid  = threadIdx.x;

  for (int i = tid; i < 16 * K3; i += 256) {
    int rr = i / K3, k = i - rr * K3;
    int row = row0 + rr;
    int b = row >> 7, n = row & 127;
    float v;
    if (k < D)          v = xbase[(long)b * xbs + n * D + k];
    else if (k < CATF)  v = h[(row << 7) + (k - D)];
    else if (k < 512)   v = D1[(row << 8) + (k - CATF)];
    else                v = D2[(row << 8) + (k - 512)];
    Al[rr][k] = v;
  }
  __syncthreads();

  const int o  = ob + (tid & 127);
  const int r0 = (tid >> 7) * 8;
  float acc[8];
#pragma unroll
  for (int i = 0; i < 8; i++) acc[i] = 0.f;
#pragma unroll 4
  for (int k = 0; k < K3; k++) {
    float w = Wgr[k * OG + o];
#pragma unroll
    for (int i = 0; i < 8; i++) acc[i] += Al[r0 + i][k] * w;
  }
#pragma unroll
  for (int i = 0; i < 8; i++) {
    int row = row0 + r0 + i;
    float g = 1.f / (1.f + __expf(-(acc[i] + bg[o])));
    if (o < H) rh[(row << 7) + o] = g * h[(row << 7) + o];
    else       u[(row << 7) + (o - H)] = g;
  }
}

// c = tanh([cat2|D1|D2] @ Wcr + bc); h = u*h + (1-u)*c; write seq (+finals at t=T-1).
// grid: 128 blocks = 128 row-blocks(16 rows); 256 threads (o=tid&127, 2 row-groups).
__global__ __launch_bounds__(256) void cand_k(
    const float* __restrict__ xbase, long xbs,
    const float* __restrict__ rh,
    const float* __restrict__ D1, const float* __restrict__ D2,
    const float* __restrict__ Wcr, const float* __restrict__ bc,
    const float* __restrict__ u, float* __restrict__ h,
    float* __restrict__ seq_out, float* __restrict__ finals_out) {
  __shared__ float Al[16][K3];
  const int row0 = blockIdx.x * 16;
  const int tid  = threadIdx.x;

  for (int i = tid; i < 16 * K3; i += 256) {
    int rr = i / K3, k = i - rr * K3;
    int row = row0 + rr;
    int b = row >> 7, n = row & 127;
    float v;
    if (k < D)          v = xbase[(long)b * xbs + n * D + k];
    else if (k < CATF)  v = rh[(row << 7) + (k - D)];
    else if (k < 512)   v = D1[(row << 8) + (k - CATF)];
    else                v = D2[(row << 8) + (k - 512)];
    Al[rr][k] = v;
  }
  __syncthreads();

  const int o  = tid & 127;
  const int r0 = (tid >> 7) * 8;
  float acc[8];
#pragma unroll
  for (int i = 0; i < 8; i++) acc[i] = 0.f;
#pragma unroll 4
  for (int k = 0; k < K3; k++) {
    float w = Wcr[k * OC + o];
#pragma unroll
    for (int i = 0; i < 8; i++) acc[i] += Al[r0 + i][k] * w;
  }
#pragma unroll
  for (int i = 0; i < 8; i++) {
    int row = row0 + r0 + i;
    float c  = tanhf(acc[i] + bc[o]);
    float uv = u[(row << 7) + o];
    float hv = h[(row << 7) + o];
    float hn = uv * hv + (1.f - uv) * c;
    h[(row << 7) + o] = hn;
    seq_out[(row << 7) + o] = hn;
    if (finals_out) finals_out[(row << 7) + o] = hn;
  }
}

extern "C" void kernel_launch(void* const* d_in, const int* in_sizes, int n_in,
                              void* d_out, int out_size, void* d_ws, size_t ws_size,
                              hipStream_t stream) {
  const float* inputs = (const float*)d_in[0];
  const float* init_h = (const float*)d_in[1];
  const float* sup    = (const float*)d_in[2];
  const float* Wg0 = (const float*)d_in[3];
  const float* bg0 = (const float*)d_in[4];
  const float* Wc0 = (const float*)d_in[5];
  const float* bc0 = (const float*)d_in[6];
  const float* Wg1 = (const float*)d_in[7];
  const float* bg1 = (const float*)d_in[8];
  const float* Wc1 = (const float*)d_in[9];
  const float* bc1 = (const float*)d_in[10];
  float* out = (float*)d_out;

  // workspace layout (floats), total ~10.8M floats (~43 MB)
  float* ws   = (float*)d_ws;
  float* Wgr  = ws;                          // 2*768*256 = 393216
  float* Wcr  = Wgr + 2 * K3 * OG;           // 2*768*128 = 196608
  float* h    = Wcr + 2 * K3 * OC;           // 262144
  float* D1   = h + ROWS * H;                // 524288
  float* D2   = D1 + ROWS * CATF;            // 524288
  float* rh   = D2 + ROWS * CATF;            // 262144
  float* uu   = rh + ROWS * H;               // 262144
  float* seq0 = uu + ROWS * H;               // T*ROWS*H = 8388608

  prep_weights_k<<<256, 256, 0, stream>>>(Wg0, Wc0, Wg1, Wc1, Wgr, Wcr);

  for (int l = 0; l < 2; l++) {
    copy_k<<<256, 256, 0, stream>>>(init_h + (long)l * ROWS * H, h, ROWS * H);
    const float* Wgl = Wgr + (long)l * K3 * OG;
    const float* Wcl = Wcr + (long)l * K3 * OC;
    const float* bgl = l ? bg1 : bg0;
    const float* bcl = l ? bc1 : bc0;
    for (int t = 0; t < T; t++) {
      const float* S = sup + (long)t * N * N;             // supports[0, t]
      const float* xbase = (l == 0) ? inputs + (long)t * N * D
                                    : seq0 + (long)t * ROWS * H;
      long xbs = (l == 0) ? (long)T * N * D : (long)N * H;

      diffusion_k<<<128, 256, 0, stream>>>(S, xbase, xbs, h, D1, D2);
      gates_k<<<256, 256, 0, stream>>>(xbase, xbs, h, D1, D2, Wgl, bgl, rh, uu);
      diffusion_k<<<128, 256, 0, stream>>>(S, xbase, xbs, rh, D1, D2);

      float* seq_out = (l == 0) ? seq0 + (long)t * ROWS * H
                                : out + (long)2 * ROWS * H + (long)t * ROWS * H;
      float* finals_out = (t == T - 1) ? out + (long)l * ROWS * H : nullptr;
      cand_k<<<128, 256, 0, stream>>>(xbase, xbs, rh, D1, D2, Wcl, bcl, uu, h,
                                      seq_out, finals_out);
    }
  }
}